// Round 1
// baseline (672.978 us; speedup 1.0000x reference)
//
#include <hip/hip_runtime.h>

#define NN 100000
#define NPAD 100096   // 391 * 256, padded row count for guard-free GEMM
#define NE 600000
#define EMB 128

typedef unsigned short u16;
typedef unsigned int u32;
typedef unsigned long long u64;
typedef _Float16 half8 __attribute__((ext_vector_type(8)));
typedef float f32x4 __attribute__((ext_vector_type(4)));

__device__ __forceinline__ float4 ld4(const float* p) { return *(const float4*)p; }
__device__ __forceinline__ u32 packh2(float a, float b) {  // two f32 -> packed f16 pair
  union { _Float16 h[2]; u32 d; } u;
  u.h[0] = (_Float16)a;
  u.h[1] = (_Float16)b;
  return u.d;
}

// ---------------- node embedding init: hb(f16) = emb1[x0] + emb2[x1] ----------------
__global__ __launch_bounds__(256) void node_init_kernel(
    const int* __restrict__ x, const float* __restrict__ emb1,
    const float* __restrict__ emb2, _Float16* __restrict__ hb) {
  int tid = blockIdx.x * blockDim.x + threadIdx.x;
  int n = tid >> 4;
  if (n >= NN) return;
  int kc = tid & 15;
  int x0 = min(max(x[2 * n], 0), 118);
  int x1 = min(max(x[2 * n + 1], 0), 2);  // x[:,1] sampled 0..118 -> clip to NUM_CHIR-1
  const float* p1 = emb1 + (size_t)x0 * EMB + kc * 8;
  const float* p2 = emb2 + (size_t)x1 * EMB + kc * 8;
  _Float16 o[8];
#pragma unroll
  for (int j = 0; j < 8; ++j) o[j] = (_Float16)(p1[j] + p2[j]);
  *(ulonglong2*)(hb + (size_t)n * EMB + kc * 8) = *(ulonglong2*)o;
}

// ---------------- CSR build ----------------
__global__ __launch_bounds__(256) void hist_kernel(const int* __restrict__ ei,
                                                   int* __restrict__ deg) {
  int e = blockIdx.x * blockDim.x + threadIdx.x;
  if (e >= NE) return;
  atomicAdd(&deg[ei[NE + e]], 1);
}

__global__ __launch_bounds__(256) void scan1_kernel(const int* __restrict__ deg,
                                                    int* __restrict__ off,
                                                    int* __restrict__ bsum) {
  __shared__ int s[256];
  int t = threadIdx.x;
  int base = blockIdx.x * 1024 + t * 4;
  int v[4];
#pragma unroll
  for (int j = 0; j < 4; ++j) {
    int idx = base + j;
    v[j] = (idx < NN) ? deg[idx] : 0;
  }
  int tsum = v[0] + v[1] + v[2] + v[3];
  s[t] = tsum;
  __syncthreads();
  for (int d = 1; d < 256; d <<= 1) {
    int add = (t >= d) ? s[t - d] : 0;
    __syncthreads();
    s[t] += add;
    __syncthreads();
  }
  int run = s[t] - tsum;
#pragma unroll
  for (int j = 0; j < 4; ++j) {
    int idx = base + j;
    if (idx < NN) off[idx] = run;
    run += v[j];
  }
  if (t == 255) bsum[blockIdx.x] = s[255];
}

__global__ void scan2_kernel(int* __restrict__ bsum, int* __restrict__ off, int nb) {
  if (threadIdx.x == 0) {
    int run = 0;
    for (int b = 0; b < nb; ++b) {
      int v = bsum[b];
      bsum[b] = run;
      run += v;
    }
    off[NN] = run;
  }
}

__global__ __launch_bounds__(256) void scan3_kernel(int* __restrict__ off,
                                                    const int* __restrict__ bsum) {
  int idx = blockIdx.x * blockDim.x + threadIdx.x;
  if (idx < NN) off[idx] += bsum[idx >> 10];
}

__global__ __launch_bounds__(256) void scatter_kernel(
    const int* __restrict__ ei, const int* __restrict__ ea,
    const int* __restrict__ off, int* __restrict__ cnt, int* __restrict__ csr) {
  int e = blockIdx.x * blockDim.x + threadIdx.x;
  if (e >= NE) return;
  int d = ei[NE + e];
  int s = ei[e];
  int a0 = min(max(ea[2 * e], 0), 4);
  int a1 = min(max(ea[2 * e + 1], 0), 2);
  int code = a0 * 3 + a1;  // [0,14]
  int r = atomicAdd(&cnt[d], 1);
  csr[off[d] + r] = s | (code << 20);
}

// combos[l][code][f] = ee1[l][code/3][f] + ee2[l][code%3][f]
__global__ __launch_bounds__(256) void combo_kernel(const float* __restrict__ ee1,
                                                    const float* __restrict__ ee2,
                                                    float* __restrict__ combos) {
  int idx = blockIdx.x * blockDim.x + threadIdx.x;
  if (idx >= 5 * 15 * 128) return;
  int l = idx / (15 * 128);
  int rem = idx % (15 * 128);
  int code = rem / 128;
  int f = rem % 128;
  combos[idx] = ee1[(l * 5 + code / 3) * 128 + f] + ee2[(l * 3 + code % 3) * 128 + f];
}

// ---------------- weight prep: frag-ordered f16 copies of W1/W2 ----------------
__global__ __launch_bounds__(256) void prep_w_kernel(
    const float* __restrict__ W1g, const float* __restrict__ W2g,
    _Float16* __restrict__ W1f, _Float16* __restrict__ W2f) {
  int idx = blockIdx.x * blockDim.x + threadIdx.x;
  if (idx >= 40960) return;
  _Float16 o[8];
  if (idx < 20480) {
    int lane = idx & 63;
    int r = idx >> 6;             // l*64 + c*16 + kt*4 + colt
    int nt = r & 3, kt = (r >> 2) & 3, c = (r >> 4) & 3, l = r >> 6;
    int n = c * 64 + nt * 16 + (lane & 15);
    int kb = kt * 32 + (lane >> 4) * 8;
#pragma unroll
    for (int j = 0; j < 8; ++j) o[j] = (_Float16)W1g[((size_t)l * 128 + kb + j) * 256 + n];
    *(ulonglong2*)(W1f + (size_t)idx * 8) = *(ulonglong2*)o;
  } else {
    int i2 = idx - 20480;
    int lane = i2 & 63;
    int r = i2 >> 6;              // l*64 + c*16 + ktl*8 + nt
    int nt = r & 7, ktl = (r >> 3) & 1, c = (r >> 4) & 3, l = r >> 6;
    int n = nt * 16 + (lane & 15);
    int kb = c * 64 + ktl * 32 + (lane >> 4) * 8;
#pragma unroll
    for (int j = 0; j < 8; ++j) o[j] = (_Float16)W2g[((size_t)l * 256 + kb + j) * 128 + n];
    *(ulonglong2*)(W2f + (size_t)i2 * 8) = *(ulonglong2*)o;
  }
}

// ---------------- agg: Af = (1+eps)*h + relu(h+c0) + sum relu(h[src]+c) ----------------
// NORM: h = relu(hsrc*sc + sh)  (BN of previous layer fused into the gather).
template <bool NORM>
__global__ __launch_bounds__(256) void agg_kernel(
    const _Float16* __restrict__ hsrc, const float* __restrict__ scsh,
    const int* __restrict__ off, const int* __restrict__ csr,
    const float* __restrict__ cb, const float* __restrict__ epsp,
    _Float16* __restrict__ Af) {
  int tid = blockIdx.x * blockDim.x + threadIdx.x;
  int g = tid >> 4;
  int kc = tid & 15;
  float av[8] = {0.f, 0.f, 0.f, 0.f, 0.f, 0.f, 0.f, 0.f};
  float scv[8], shv[8];
  if (NORM) {
    float4 sa = ld4(scsh + kc * 8), sb = ld4(scsh + kc * 8 + 4);
    float4 ha = ld4(scsh + 128 + kc * 8), hbv = ld4(scsh + 128 + kc * 8 + 4);
    scv[0] = sa.x; scv[1] = sa.y; scv[2] = sa.z; scv[3] = sa.w;
    scv[4] = sb.x; scv[5] = sb.y; scv[6] = sb.z; scv[7] = sb.w;
    shv[0] = ha.x; shv[1] = ha.y; shv[2] = ha.z; shv[3] = ha.w;
    shv[4] = hbv.x; shv[5] = hbv.y; shv[6] = hbv.z; shv[7] = hbv.w;
  }
  if (g < NN) {
    const float eps1 = 1.0f + *epsp;
    ulonglong2 hraw = *(const ulonglong2*)(hsrc + (size_t)g * EMB + kc * 8);
    _Float16* hr = (_Float16*)&hraw;
    float4 ca = ld4(cb + kc * 8), cbv = ld4(cb + kc * 8 + 4);
    float cs[8] = {ca.x, ca.y, ca.z, ca.w, cbv.x, cbv.y, cbv.z, cbv.w};
#pragma unroll
    for (int j = 0; j < 8; ++j) {
      float hv = (float)hr[j];
      if (NORM) hv = fmaxf(hv * scv[j] + shv[j], 0.f);
      av[j] = eps1 * hv + fmaxf(hv + cs[j], 0.f);
    }
    int s0 = off[g], s1 = off[g + 1];
    int e = s0;
    for (; e + 3 < s1; e += 4) {  // unroll x4: four gather chains in flight
      int p0 = csr[e], p1 = csr[e + 1], p2 = csr[e + 2], p3 = csr[e + 3];
      ulonglong2 r0 = *(const ulonglong2*)(hsrc + (size_t)(p0 & 0xFFFFF) * EMB + kc * 8);
      ulonglong2 r1 = *(const ulonglong2*)(hsrc + (size_t)(p1 & 0xFFFFF) * EMB + kc * 8);
      ulonglong2 r2 = *(const ulonglong2*)(hsrc + (size_t)(p2 & 0xFFFFF) * EMB + kc * 8);
      ulonglong2 r3 = *(const ulonglong2*)(hsrc + (size_t)(p3 & 0xFFFFF) * EMB + kc * 8);
      ulonglong2 rr[4] = {r0, r1, r2, r3};
      int pp[4] = {p0, p1, p2, p3};
#pragma unroll
      for (int u = 0; u < 4; ++u) {
        const float* cp = cb + (size_t)(pp[u] >> 20) * EMB + kc * 8;
        float4 c0 = ld4(cp), c1 = ld4(cp + 4);
        float cc[8] = {c0.x, c0.y, c0.z, c0.w, c1.x, c1.y, c1.z, c1.w};
        _Float16* sp = (_Float16*)&rr[u];
#pragma unroll
        for (int j = 0; j < 8; ++j) {
          float v = (float)sp[j];
          if (NORM) v = fmaxf(v * scv[j] + shv[j], 0.f);
          av[j] += fmaxf(v + cc[j], 0.f);
        }
      }
    }
    for (; e < s1; ++e) {
      int p0 = csr[e];
      ulonglong2 r0 = *(const ulonglong2*)(hsrc + (size_t)(p0 & 0xFFFFF) * EMB + kc * 8);
      const float* cp = cb + (size_t)(p0 >> 20) * EMB + kc * 8;
      float4 c0 = ld4(cp), c1 = ld4(cp + 4);
      float cc[8] = {c0.x, c0.y, c0.z, c0.w, c1.x, c1.y, c1.z, c1.w};
      _Float16* sp = (_Float16*)&r0;
#pragma unroll
      for (int j = 0; j < 8; ++j) {
        float v = (float)sp[j];
        if (NORM) v = fmaxf(v * scv[j] + shv[j], 0.f);
        av[j] += fmaxf(v + cc[j], 0.f);
      }
    }
  }
  _Float16 o[8];
#pragma unroll
  for (int j = 0; j < 8; ++j) o[j] = (_Float16)av[j];
  *(ulonglong2*)(Af + (size_t)g * EMB + kc * 8) = *(ulonglong2*)o;  // zeros for pad rows
}

// ---------------- mlp v2: weights fully LDS-resident (128KB), zero barriers in loop ----
// 8 waves x 32 nodes = 256 nodes/block, grid = NPAD/256 = 391.
// Each W-fragment ds_read is reused for 2 node-tiles -> 4KB LDS read per node
// (balanced with 32 CU-cycles/node of MFMA). No per-chunk staging, no sync.
__global__ __launch_bounds__(512, 2) void mlp_kernel(
    const _Float16* __restrict__ Af, const _Float16* __restrict__ W1f,
    const _Float16* __restrict__ W2f,
    const float* __restrict__ b1g, const float* __restrict__ b2g,
    _Float16* __restrict__ hpre, float* __restrict__ slots) {
  extern __shared__ __align__(16) _Float16 Ws[];  // 128KB: W1 (32768) then W2 (32768)
  _Float16* W1s = Ws;
  _Float16* W2s = Ws + 32768;

  const int t = threadIdx.x;
  const int w = t >> 6;
  const int lane = t & 63;
  const int q = lane >> 4, l15 = lane & 15;
  const int gw = blockIdx.x * 8 + w;
  const int n0 = blockIdx.x * 256 + w * 32;  // 32 nodes per wave
  float* sums = slots + (size_t)(gw & 31) * 256;

  // ---- A fragments: issue early so HBM latency hides under weight staging ----
  half8 nh[2][4];
#pragma unroll
  for (int ntile = 0; ntile < 2; ++ntile)
#pragma unroll
    for (int kt = 0; kt < 4; ++kt)
      nh[ntile][kt] =
          *(const half8*)(Af + (size_t)(n0 + ntile * 16 + l15) * EMB + kt * 32 + q * 8);

  // ---- one-time cooperative weight load: full W1 + W2 layer into LDS ----
  {
    ulonglong2* d1 = (ulonglong2*)W1s;
    ulonglong2* d2 = (ulonglong2*)W2s;
    const ulonglong2* g1 = (const ulonglong2*)W1f;
    const ulonglong2* g2 = (const ulonglong2*)W2f;
#pragma unroll
    for (int j = 0; j < 8; ++j) d1[t + j * 512] = g1[t + j * 512];
#pragma unroll
    for (int j = 0; j < 8; ++j) d2[t + j * 512] = g2[t + j * 512];
  }
  __syncthreads();  // the ONLY barrier

  f32x4 oacc[2][8];  // [ntile][out col tile]
#pragma unroll
  for (int ntile = 0; ntile < 2; ++ntile)
#pragma unroll
    for (int a = 0; a < 8; ++a) oacc[ntile][a] = (f32x4){0.f, 0.f, 0.f, 0.f};

  const int srcA = ((q & 1) * 2) * 16 + l15;  // quad permutation sources
  const int srcB = srcA + 16;
  const bool sel = (q >> 1) != 0;

  for (int c = 0; c < 4; ++c) {
    // ---- stage 1: hmidT[col c*64+colt*16+q*4+r][node l15] per ntile ----
    f32x4 hacc[2][4];
#pragma unroll
    for (int ntile = 0; ntile < 2; ++ntile)
#pragma unroll
      for (int a = 0; a < 4; ++a) hacc[ntile][a] = (f32x4){0.f, 0.f, 0.f, 0.f};
#pragma unroll
    for (int kt = 0; kt < 4; ++kt) {
      half8 wh[4];
#pragma unroll
      for (int colt = 0; colt < 4; ++colt)
        wh[colt] = *(const half8*)&W1s[(c * 16 + kt * 4 + colt) * 512 + lane * 8];
#pragma unroll
      for (int colt = 0; colt < 4; ++colt) {
        hacc[0][colt] =
            __builtin_amdgcn_mfma_f32_16x16x32_f16(wh[colt], nh[0][kt], hacc[0][colt], 0, 0, 0);
        hacc[1][colt] =
            __builtin_amdgcn_mfma_f32_16x16x32_f16(wh[colt], nh[1][kt], hacc[1][colt], 0, 0, 0);
      }
    }

    // ---- bias + relu + pack to f16 pairs ----
    u32 P01[2][4], P23[2][4];  // [ntile][colt]
#pragma unroll
    for (int colt = 0; colt < 4; ++colt) {
      float4 b1v = ld4(b1g + c * 64 + colt * 16 + q * 4);
#pragma unroll
      for (int ntile = 0; ntile < 2; ++ntile) {
        float v0 = fmaxf(hacc[ntile][colt][0] + b1v.x, 0.f);
        float v1 = fmaxf(hacc[ntile][colt][1] + b1v.y, 0.f);
        float v2 = fmaxf(hacc[ntile][colt][2] + b1v.z, 0.f);
        float v3 = fmaxf(hacc[ntile][colt][3] + b1v.w, 0.f);
        P01[ntile][colt] = packh2(v0, v1);
        P23[ntile][colt] = packh2(v2, v3);
      }
    }

    // ---- stage 2: quad-permute hmid into B-frags, multiply with W2 from LDS ----
#pragma unroll
    for (int ktl = 0; ktl < 2; ++ktl) {
      half8 bh[2];
#pragma unroll
      for (int ntile = 0; ntile < 2; ++ntile) {
        union { u32 d[4]; half8 s; } uh;
        int c0 = 2 * ktl, c1 = 2 * ktl + 1;
        u32 a0, a1;
        a0 = (u32)__shfl((int)P01[ntile][c0], srcA);
        a1 = (u32)__shfl((int)P01[ntile][c1], srcA);
        uh.d[0] = sel ? a1 : a0;
        a0 = (u32)__shfl((int)P23[ntile][c0], srcA);
        a1 = (u32)__shfl((int)P23[ntile][c1], srcA);
        uh.d[1] = sel ? a1 : a0;
        a0 = (u32)__shfl((int)P01[ntile][c0], srcB);
        a1 = (u32)__shfl((int)P01[ntile][c1], srcB);
        uh.d[2] = sel ? a1 : a0;
        a0 = (u32)__shfl((int)P23[ntile][c0], srcB);
        a1 = (u32)__shfl((int)P23[ntile][c1], srcB);
        uh.d[3] = sel ? a1 : a0;
        bh[ntile] = uh.s;
      }
#pragma unroll
      for (int nt = 0; nt < 8; ++nt) {
        half8 wh = *(const half8*)&W2s[(c * 16 + ktl * 8 + nt) * 512 + lane * 8];
        oacc[0][nt] = __builtin_amdgcn_mfma_f32_16x16x32_f16(wh, bh[0], oacc[0][nt], 0, 0, 0);
        oacc[1][nt] = __builtin_amdgcn_mfma_f32_16x16x32_f16(wh, bh[1], oacc[1][nt], 0, 0, 0);
      }
    }
  }

  // ---- epilogue: +b2, packed f16 store (8B), BN partials into slot ----
#pragma unroll
  for (int nt = 0; nt < 8; ++nt) {
    int ocb = nt * 16 + q * 4;  // 4 consecutive out cols per lane
    float4 b2v = ld4(b2g + ocb);
    f32x4 s = (f32x4){0.f, 0.f, 0.f, 0.f};
    f32x4 s2 = (f32x4){0.f, 0.f, 0.f, 0.f};
#pragma unroll
    for (int ntile = 0; ntile < 2; ++ntile) {
      int node = n0 + ntile * 16 + l15;
      if (node < NN) {
        float v0 = oacc[ntile][nt][0] + b2v.x;
        float v1 = oacc[ntile][nt][1] + b2v.y;
        float v2 = oacc[ntile][nt][2] + b2v.z;
        float v3 = oacc[ntile][nt][3] + b2v.w;
        u64 pk = (u64)packh2(v0, v1) | ((u64)packh2(v2, v3) << 32);
        *(u64*)(hpre + (size_t)node * EMB + ocb) = pk;
        s[0] += v0; s[1] += v1; s[2] += v2; s[3] += v3;
        s2[0] += v0 * v0; s2[1] += v1 * v1; s2[2] += v2 * v2; s2[3] += v3 * v3;
      }
    }
#pragma unroll
    for (int d = 1; d < 16; d <<= 1) {
#pragma unroll
      for (int r = 0; r < 4; ++r) {
        s[r] += __shfl_xor(s[r], d);
        s2[r] += __shfl_xor(s2[r], d);
      }
    }
    if (l15 == 0) {
#pragma unroll
      for (int r = 0; r < 4; ++r) {
        atomicAdd(&sums[ocb + r], s[r]);
        atomicAdd(&sums[128 + ocb + r], s2[r]);
      }
    }
  }
}

// ---------------- stats: reduce 32 slots -> scale/shift (sc, sh) ----------------
__global__ void stats_kernel(const float* __restrict__ slots,
                             const float* __restrict__ gamma,
                             const float* __restrict__ beta,
                             float* __restrict__ scsh) {
  int f = threadIdx.x;  // 128
  float s = 0.f, s2 = 0.f;
#pragma unroll 8
  for (int k = 0; k < 32; ++k) {
    s += slots[k * 256 + f];
    s2 += slots[k * 256 + 128 + f];
  }
  float mean = s * (1.0f / NN);
  float var = s2 * (1.0f / NN) - mean * mean;  // biased
  float sc = gamma[f] * rsqrtf(var + 1e-5f);
  scsh[f] = sc;
  scsh[128 + f] = beta[f] - mean * sc;
}

// ---------------- final output: out = hpre*sc + sh (f32, no relu) ----------------
__global__ __launch_bounds__(256) void out_kernel(
    const _Float16* __restrict__ hpre, const float* __restrict__ scsh,
    float* __restrict__ out) {
  int tid = blockIdx.x * blockDim.x + threadIdx.x;
  int n = tid >> 4;
  if (n >= NN) return;
  int kc = tid & 15;
  ulonglong2 raw = *(const ulonglong2*)(hpre + (size_t)n * EMB + kc * 8);
  _Float16* hr = (_Float16*)&raw;
  float4 sa = ld4(scsh + kc * 8), sb = ld4(scsh + kc * 8 + 4);
  float4 ha = ld4(scsh + 128 + kc * 8), hbv = ld4(scsh + 128 + kc * 8 + 4);
  float scv[8] = {sa.x, sa.y, sa.z, sa.w, sb.x, sb.y, sb.z, sb.w};
  float shv[8] = {ha.x, ha.y, ha.z, ha.w, hbv.x, hbv.y, hbv.z, hbv.w};
  float v[8];
#pragma unroll
  for (int j = 0; j < 8; ++j) v[j] = (float)hr[j] * scv[j] + shv[j];
  float* d = out + (size_t)n * EMB + kc * 8;
  *(float4*)d = make_float4(v[0], v[1], v[2], v[3]);
  *(float4*)(d + 4) = make_float4(v[4], v[5], v[6], v[7]);
}

// ---------------- launch ----------------
extern "C" void kernel_launch(void* const* d_in, const int* in_sizes, int n_in,
                              void* d_out, int out_size, void* d_ws, size_t ws_size,
                              hipStream_t stream) {
  const int* x = (const int*)d_in[0];
  const int* ei = (const int*)d_in[1];
  const int* ea = (const int*)d_in[2];
  const float* x_emb1 = (const float*)d_in[3];
  const float* x_emb2 = (const float*)d_in[4];
  const float* ee1 = (const float*)d_in[5];
  const float* ee2 = (const float*)d_in[6];
  const float* W1 = (const float*)d_in[7];
  const float* b1 = (const float*)d_in[8];
  const float* W2 = (const float*)d_in[9];
  const float* b2 = (const float*)d_in[10];
  const float* eps = (const float*)d_in[11];
  const float* gamma = (const float*)d_in[12];
  const float* beta = (const float*)d_in[13];
  float* out = (float*)d_out;

  // allow 128KB dynamic LDS for mlp_kernel (host-side, once; safe under graph capture)
  static int _attr_once = []() {
    hipFuncSetAttribute((const void*)mlp_kernel,
                        hipFuncAttributeMaxDynamicSharedMemorySize, 131072);
    return 0;
  }();
  (void)_attr_once;

  // workspace layout (16B-aligned sections)
  float* slots = (float*)d_ws;                  // 5*32*256 BN partial slots
  float* scsh = slots + 5 * 32 * 256;           // 5*256 scale/shift
  float* combos = scsh + 5 * 256;               // 9600
  _Float16* hpre = (_Float16*)(combos + 9600);  // NN*128 f16
  _Float16* Af = hpre + (size_t)NN * EMB;       // NPAD*128 f16
  _Float16* hb = Af + (size_t)NPAD * EMB;       // NN*128 f16
  _Float16* W1f = hb + (size_t)NN * EMB;        // 5*32768 f16
  _Float16* W2f = W1f + 5 * 32768;              // 5*32768 f16
  int* deg = (int*)(W2f + 5 * 32768);           // NN
  int* off = deg + NN;                          // NN+1
  int* csr = off + NN + 1;                      // NE
  int* bsum = csr + NE;                         // 128

  const int NB_SCAN = (NN + 1023) / 1024;

  // one-time per launch: CSR + combo tables + frag-ordered f16 weights
  hipMemsetAsync(deg, 0, NN * sizeof(int), stream);
  hipMemsetAsync(slots, 0, 5 * 32 * 256 * sizeof(float), stream);
  hist_kernel<<<(NE + 255) / 256, 256, 0, stream>>>(ei, deg);
  scan1_kernel<<<NB_SCAN, 256, 0, stream>>>(deg, off, bsum);
  scan2_kernel<<<1, 64, 0, stream>>>(bsum, off, NB_SCAN);
  scan3_kernel<<<(NN + 255) / 256, 256, 0, stream>>>(off, bsum);
  hipMemsetAsync(deg, 0, NN * sizeof(int), stream);
  scatter_kernel<<<(NE + 255) / 256, 256, 0, stream>>>(ei, ea, off, deg, csr);
  combo_kernel<<<(5 * 15 * 128 + 255) / 256, 256, 0, stream>>>(ee1, ee2, combos);
  prep_w_kernel<<<160, 256, 0, stream>>>(W1, W2, W1f, W2f);
  node_init_kernel<<<NN * 16 / 256 + 1, 256, 0, stream>>>(x, x_emb1, x_emb2, hb);

  const int MLP_GRID = NPAD / 256;  // 391 blocks x 8 waves (32 nodes each)
  for (int i = 0; i < 5; ++i) {
    if (i == 0)
      agg_kernel<false><<<NPAD * 16 / 256, 256, 0, stream>>>(
          hb, nullptr, off, csr, combos + (size_t)i * 15 * EMB, eps + i, Af);
    else
      agg_kernel<true><<<NPAD * 16 / 256, 256, 0, stream>>>(
          hpre, scsh + (size_t)(i - 1) * 256, off, csr,
          combos + (size_t)i * 15 * EMB, eps + i, Af);
    mlp_kernel<<<MLP_GRID, 512, 131072, stream>>>(
        Af, W1f + (size_t)i * 32768, W2f + (size_t)i * 32768,
        b1 + (size_t)i * 256, b2 + (size_t)i * 128, hpre,
        slots + (size_t)i * 32 * 256);
    stats_kernel<<<1, 128, 0, stream>>>(slots + (size_t)i * 32 * 256,
                                        gamma + (size_t)i * EMB,
                                        beta + (size_t)i * EMB,
                                        scsh + (size_t)i * 256);
  }
  out_kernel<<<NN * 16 / 256 + 1, 256, 0, stream>>>(hpre, scsh + 4 * 256, out);
}